// Round 16
// baseline (32.317 us; speedup 1.0000x reference)
//
#include <hip/hip_runtime.h>

#define NN 128   // modes

// ---- whole-wave lane shifts via DPP (wave_shl:1 / wave_shr:1), proven R9-R15 ----
__device__ __forceinline__ float wshl1(float x) {   // lane i <- lane i+1
    return __int_as_float(__builtin_amdgcn_update_dpp(
        __float_as_int(x), __float_as_int(x), 0x130, 0xf, 0xf, false));
}
__device__ __forceinline__ float wshr1(float x) {   // lane i <- lane i-1
    return __int_as_float(__builtin_amdgcn_update_dpp(
        __float_as_int(x), __float_as_int(x), 0x138, 0xf, 0xf, false));
}

// (cos,sin) pair for the lane's two even rows of one layer
__device__ __forceinline__ float4 make_cs(float2 th) {
    float s0, c0, s1, c1;
    __sincosf(th.x, &s0, &c0);
    __sincosf(th.y, &s1, &c1);
    return make_float4(c0, s0, c1, s1);
}

__device__ __forceinline__ float2 cmuladd(float2 acc, float2 x, float2 y) {
    acc.x += x.x * y.x - x.y * y.y;
    acc.y += x.x * y.y + x.y * y.x;
    return acc;
}

// ---- 127 layers J0..J0+126, R15 fused structure (static ring, dist-7, DPP) ----
// On exit cf = cs(theta[J0+127]) (for J0=127: the fold coefficients).
template<int J0>
__device__ __forceinline__ float4 run127(const float2* __restrict__ TL, const int l,
                                         float2& v0, float2& v1, float2& v2, float2& v3)
{
    const float A  = sqrtf(0.95f * 0.505f);
    const float B  = sqrtf(0.95f * 0.495f);
    const float C2 = sqrtf(0.98f * 0.01f);
    const float S2 = sqrtf(0.98f * 0.99f);
    const float ec0 = (l == 0)  ? S2 : C2, es0 = (l == 0)  ? 0.f : S2;
    const float ec3 = (l == 63) ? S2 : C2, es3 = (l == 63) ? 0.f : S2;

    float2 t0 = TL[(J0+0)*64], t1 = TL[(J0+1)*64], t2 = TL[(J0+2)*64],
           t3 = TL[(J0+3)*64], t4 = TL[(J0+4)*64], t5 = TL[(J0+5)*64],
           t6 = TL[(J0+6)*64], t7 = TL[(J0+7)*64];

    auto layer = [&](float4 t) {
        float rx = t.x * v0.x - t.y * v0.y;     // e^{i th} * v0
        float ry = t.x * v0.y + t.y * v0.x;
        float qx = t.z * v2.x - t.w * v2.y;     // e^{i th'} * v2
        float qy = t.z * v2.y + t.w * v2.x;
        float2 n0, n1, n2, n3;
        n0.x = A * rx   - B * v1.y;  n0.y = A * ry   + B * v1.x;
        n1.x = A * v1.x - B * ry;    n1.y = A * v1.y + B * rx;
        n2.x = A * qx   - B * v3.y;  n2.y = A * qy   + B * v3.x;
        n3.x = A * v3.x - B * qy;    n3.y = A * v3.y + B * qx;
        v0 = n0; v1 = n1; v2 = n2; v3 = n3;
    };
    auto crossl = [&]() {
        float nx = wshl1(v0.x), ny = wshl1(v0.y);   // lane l+1's v0
        float px = wshr1(v3.x), py = wshr1(v3.y);   // lane l-1's v3
        float2 m0, m1, m2, m3;
        m0.x = ec0 * v0.x - es0 * py;  m0.y = ec0 * v0.y + es0 * px;
        m3.x = ec3 * v3.x - es3 * ny;  m3.y = ec3 * v3.y + es3 * nx;
        m1.x = C2 * v1.x - S2 * v2.y;  m1.y = C2 * v1.y + S2 * v2.x;
        m2.x = C2 * v2.x - S2 * v1.y;  m2.y = C2 * v2.y + S2 * v1.x;
        v0 = m0; v1 = m1; v2 = m2; v3 = m3;
    };

    float4 cf = make_cs(t0);   // layer J0 coefficients

    // 15 batches of 8: layers J0..J0+119. Max load index = J0+127 (<=254, no clamp).
    for (int j8 = J0; j8 < J0 + 120; j8 += 8) {
        { t0 = TL[(j8+ 8)*64]; float4 cfn = make_cs(t1); layer(cf); if (((J0+0)&1)==0) crossl(); cf = cfn; }
        { t1 = TL[(j8+ 9)*64]; float4 cfn = make_cs(t2); layer(cf); if (((J0+1)&1)==0) crossl(); cf = cfn; }
        { t2 = TL[(j8+10)*64]; float4 cfn = make_cs(t3); layer(cf); if (((J0+2)&1)==0) crossl(); cf = cfn; }
        { t3 = TL[(j8+11)*64]; float4 cfn = make_cs(t4); layer(cf); if (((J0+3)&1)==0) crossl(); cf = cfn; }
        { t4 = TL[(j8+12)*64]; float4 cfn = make_cs(t5); layer(cf); if (((J0+4)&1)==0) crossl(); cf = cfn; }
        { t5 = TL[(j8+13)*64]; float4 cfn = make_cs(t6); layer(cf); if (((J0+5)&1)==0) crossl(); cf = cfn; }
        { t6 = TL[(j8+14)*64]; float4 cfn = make_cs(t7); layer(cf); if (((J0+6)&1)==0) crossl(); cf = cfn; }
        { t7 = TL[(j8+15)*64]; float4 cfn = make_cs(t0); layer(cf); if (((J0+7)&1)==0) crossl(); cf = cfn; }
    }
    // tail: layers J0+120..J0+126 (7 layers); t0..t7 hold theta[J0+120..J0+127]
    { float4 cfn = make_cs(t1); layer(cf); if (((J0+0)&1)==0) crossl(); cf = cfn; }
    { float4 cfn = make_cs(t2); layer(cf); if (((J0+1)&1)==0) crossl(); cf = cfn; }
    { float4 cfn = make_cs(t3); layer(cf); if (((J0+2)&1)==0) crossl(); cf = cfn; }
    { float4 cfn = make_cs(t4); layer(cf); if (((J0+3)&1)==0) crossl(); cf = cfn; }
    { float4 cfn = make_cs(t5); layer(cf); if (((J0+4)&1)==0) crossl(); cf = cfn; }
    { float4 cfn = make_cs(t6); layer(cf); if (((J0+5)&1)==0) crossl(); cf = cfn; }
    { float4 cfn = make_cs(t7); layer(cf); if (((J0+6)&1)==0) crossl(); cf = cfn; }
    return cf;   // cs(theta[J0+127])
}

// ---------------- kernel 1: both phases ----------------
// blocks 0..127   : phase A, column c through layers 0..126 -> M1T[c][g]
// blocks 128..383 : phase B, basis column g through layers 127..253 + fold -> T2T[g][n]
__global__ __launch_bounds__(64) void phase_kernel(
    const float* __restrict__ theta_in,    // (128,)
    const float* __restrict__ theta_even,  // (255,128)
    float2* __restrict__ M1T,              // [128][256]
    float2* __restrict__ T2T)              // [256][128]
{
    const int bid = blockIdx.x;
    const int l = threadIdx.x;
    const float A = sqrtf(0.95f * 0.505f);
    const float B = sqrtf(0.95f * 0.495f);
    const float2* TL = (const float2*)theta_even + l;

    float2 v0 = make_float2(0.f, 0.f), v1 = v0, v2 = v0, v3 = v0;

    if (bid < 128) {
        const int c = bid;
        float s, co;
        __sincosf(theta_in[c], &s, &co);
        if (l == (c >> 1)) {
            float2 e0 = make_float2(A * co, A * s);
            float2 e1 = make_float2(-B * s, B * co);
            if (c & 1) { v2 = e0; v3 = e1; }
            else       { v0 = e0; v1 = e1; }
        }
        run127<0>(TL, l, v0, v1, v2, v3);
        float4* dst = (float4*)(M1T + (size_t)c * 256 + 4 * l);
        dst[0] = make_float4(v0.x, v0.y, v1.x, v1.y);
        dst[1] = make_float4(v2.x, v2.y, v3.x, v3.y);
    } else {
        const int g = bid - 128;
        if (l == (g >> 2)) {
            float2 one = make_float2(1.f, 0.f);
            int k = g & 3;
            if      (k == 0) v0 = one;
            else if (k == 1) v1 = one;
            else if (k == 2) v2 = one;
            else             v3 = one;
        }
        float4 cf = run127<127>(TL, l, v0, v1, v2, v3);   // cf = cs(theta[254])
        // fold: diag(theta[254]) + MMI_OUT -> rows 2l, 2l+1 of T2
        float rx = cf.x * v0.x - cf.y * v0.y;
        float ry = cf.x * v0.y + cf.y * v0.x;
        float qx = cf.z * v2.x - cf.w * v2.y;
        float qy = cf.z * v2.y + cf.w * v2.x;
        float4 o;
        o.x = A * rx - B * v1.y;  o.y = A * ry + B * v1.x;   // row 2l
        o.z = A * qx - B * v3.y;  o.w = A * qy + B * v3.x;   // row 2l+1
        *(float4*)(T2T + (size_t)g * 128 + 2 * l) = o;
    }
}

// ---------------- kernel 2: combine + epilogue (R12 proven) ----------------
// out[n][c] = Re( e^{i th_out[n]} * sum_g T2[n][g] * M1[g][c] )
__global__ __launch_bounds__(64) void combine_kernel(
    const float2* __restrict__ M1T,        // [128][256]
    const float2* __restrict__ T2T,        // [256][128]
    const float* __restrict__ theta_out,   // (128,)
    float* __restrict__ out)               // (128,128)
{
    const int c = blockIdx.x;
    const int l = threadIdx.x;
    const float2* m1 = M1T + (size_t)c * 256;

    float2 acc0 = make_float2(0.f, 0.f), acc1 = acc0;
    #pragma unroll 8
    for (int g = 0; g < 256; ++g) {
        float2 m = m1[g];                                            // wave-uniform
        float4 t = *(const float4*)(T2T + (size_t)g * 128 + 2 * l);  // coalesced
        acc0 = cmuladd(acc0, make_float2(t.x, t.y), m);
        acc1 = cmuladd(acc1, make_float2(t.z, t.w), m);
    }

    float2 tho = ((const float2*)theta_out)[l];
    float s0, c0, s1, c1;
    __sincosf(tho.x, &s0, &c0);
    __sincosf(tho.y, &s1, &c1);
    out[(2 * l)     * NN + c] = c0 * acc0.x - s0 * acc0.y;
    out[(2 * l + 1) * NN + c] = c1 * acc1.x - s1 * acc1.y;
}

// ---------------- fallback: R15 single fused kernel (no ws needed) ----------------
__global__ __launch_bounds__(64) void mesh_fused_kernel(
    const float* __restrict__ theta_in, const float* __restrict__ theta_even,
    const float* __restrict__ theta_out, float* __restrict__ out)
{
    const int c = blockIdx.x;
    const int l = threadIdx.x;
    const float A = sqrtf(0.95f * 0.505f);
    const float B = sqrtf(0.95f * 0.495f);
    const float2* TL = (const float2*)theta_even + l;

    float2 v0 = make_float2(0.f, 0.f), v1 = v0, v2 = v0, v3 = v0;
    {
        float s, co;
        __sincosf(theta_in[c], &s, &co);
        if (l == (c >> 1)) {
            float2 e0 = make_float2(A * co, A * s);
            float2 e1 = make_float2(-B * s, B * co);
            if (c & 1) { v2 = e0; v3 = e1; }
            else       { v0 = e0; v1 = e1; }
        }
    }
    run127<0>(TL, l, v0, v1, v2, v3);
    float4 cf = run127<127>(TL, l, v0, v1, v2, v3);
    float rx = cf.x * v0.x - cf.y * v0.y;
    float ry = cf.x * v0.y + cf.y * v0.x;
    float qx = cf.z * v2.x - cf.w * v2.y;
    float qy = cf.z * v2.y + cf.w * v2.x;
    float2 o0, o1;
    o0.x = A * rx - B * v1.y;  o0.y = A * ry + B * v1.x;
    o1.x = A * qx - B * v3.y;  o1.y = A * qy + B * v3.x;
    float2 tho = ((const float2*)theta_out)[l];
    float s0, c0, s1, c1;
    __sincosf(tho.x, &s0, &c0);
    __sincosf(tho.y, &s1, &c1);
    out[(2 * l)     * NN + c] = c0 * o0.x - s0 * o0.y;
    out[(2 * l + 1) * NN + c] = c1 * o1.x - s1 * o1.y;
}

extern "C" void kernel_launch(void* const* d_in, const int* in_sizes, int n_in,
                              void* d_out, int out_size, void* d_ws, size_t ws_size,
                              hipStream_t stream) {
    // Identify inputs by SIZE: theta_even is the unique large (32640) array;
    // the two 128-elem arrays keep relative order (theta_in before theta_out).
    int ev = 0;
    for (int i = 0; i < n_in; ++i) if (in_sizes[i] > 1000) ev = i;
    int a = -1, b = -1;
    for (int i = 0; i < n_in; ++i) {
        if (i == ev) continue;
        if (a < 0) a = i; else if (b < 0) b = i;
    }
    const float* th_in  = (const float*)d_in[a];
    const float* th_ev  = (const float*)d_in[ev];
    const float* th_out = (const float*)d_in[b];

    const size_t m1_bytes = (size_t)128 * 256 * sizeof(float2);   // 256 KB
    const size_t t2_bytes = (size_t)256 * 128 * sizeof(float2);   // 256 KB
    if (ws_size >= m1_bytes + t2_bytes) {
        float2* M1T = (float2*)d_ws;
        float2* T2T = (float2*)((char*)d_ws + m1_bytes);
        phase_kernel<<<dim3(384), dim3(64), 0, stream>>>(th_in, th_ev, M1T, T2T);
        combine_kernel<<<dim3(128), dim3(64), 0, stream>>>(M1T, T2T, th_out, (float*)d_out);
    } else {
        mesh_fused_kernel<<<dim3(NN), dim3(64), 0, stream>>>(th_in, th_ev, th_out, (float*)d_out);
    }
}